// Round 4
// baseline (521.862 us; speedup 1.0000x reference)
//
#include <hip/hip_runtime.h>

typedef __attribute__((ext_vector_type(8))) short short8;
typedef __attribute__((ext_vector_type(4))) float f32x4;

constexpr int T_STEPS = 32;
constexpr int BATCH   = 32;
constexpr int DG      = 256;
constexpr int DH      = 512;
constexpr int NHIST   = 31;
constexpr int WPB     = 2;      // batches per block
constexpr float LAMBDA_ = 0.95f;
constexpr float ETA_    = 0.5f;
constexpr float EPS_    = 1e-5f;

__device__ __forceinline__ uint bf16cvt(float f) {
  uint u = __float_as_uint(f);
  return (u + 0x7FFFu + ((u >> 16) & 1u)) >> 16;
}

// aux: blocks 0..255 -> ZG = z @ Wg^T + bh ; blocks 256..319 -> pack W_h into
// MFMA A-fragment layout: Wp[(mt*16+kk)*64 + lane] = uint4 of 8 bf16 =
// W[mt*16 + (lane&15)][kk*32 + (lane>>4)*8 .. +8), lo-first pairs.
__global__ __launch_bounds__(512) void aux_kernel(
    const float* __restrict__ z, const float* __restrict__ Wg,
    const float* __restrict__ bh, float* __restrict__ ZG,
    const float* __restrict__ Wh, uint4* __restrict__ Wp) {
  const int tid = threadIdx.x;
  if (blockIdx.x < 256) {
    const int lane = tid & 63;
    const int wave = tid >> 6;   // 0..7
    const int tb0  = blockIdx.x * 4;
    float4 zv[4];
#pragma unroll
    for (int p = 0; p < 4; ++p)
      zv[p] = *reinterpret_cast<const float4*>(z + (size_t)(tb0 + p) * DG + lane * 4);
    for (int k = 0; k < 64; ++k) {
      const int r = wave * 64 + k;
      const float4 wv = *reinterpret_cast<const float4*>(Wg + (size_t)r * DG + lane * 4);
      float a0 = zv[0].x*wv.x + zv[0].y*wv.y + zv[0].z*wv.z + zv[0].w*wv.w;
      float a1 = zv[1].x*wv.x + zv[1].y*wv.y + zv[1].z*wv.z + zv[1].w*wv.w;
      float a2 = zv[2].x*wv.x + zv[2].y*wv.y + zv[2].z*wv.z + zv[2].w*wv.w;
      float a3 = zv[3].x*wv.x + zv[3].y*wv.y + zv[3].z*wv.z + zv[3].w*wv.w;
#pragma unroll
      for (int off = 32; off; off >>= 1) {
        a0 += __shfl_xor(a0, off, 64);
        a1 += __shfl_xor(a1, off, 64);
        a2 += __shfl_xor(a2, off, 64);
        a3 += __shfl_xor(a3, off, 64);
      }
      if (lane == 0) {
        const float bb = bh[r];
        ZG[(size_t)(tb0 + 0) * DH + r] = a0 + bb;
        ZG[(size_t)(tb0 + 1) * DH + r] = a1 + bb;
        ZG[(size_t)(tb0 + 2) * DH + r] = a2 + bb;
        ZG[(size_t)(tb0 + 3) * DH + r] = a3 + bb;
      }
    }
  } else {
    const int f  = (blockIdx.x - 256) * 512 + tid;   // 0..32767
    const int lf = f & 63;
    const int kk = (f >> 6) & 15;
    const int mt = f >> 10;
    const int r  = mt * 16 + (lf & 15);
    const int k0 = kk * 32 + (lf >> 4) * 8;
    const float4 a = *reinterpret_cast<const float4*>(Wh + (size_t)r * DH + k0);
    const float4 b = *reinterpret_cast<const float4*>(Wh + (size_t)r * DH + k0 + 4);
    uint4 o;
    o.x = bf16cvt(a.x) | (bf16cvt(a.y) << 16);
    o.y = bf16cvt(a.z) | (bf16cvt(a.w) << 16);
    o.z = bf16cvt(b.x) | (bf16cvt(b.y) << 16);
    o.w = bf16cvt(b.z) | (bf16cvt(b.w) << 16);
    Wp[f] = o;
  }
}

// Serial recurrence: 16 blocks x 1024 threads, 2 batches/block.
// matvec hb = Wh.h for both batches via mfma_f32_16x16x32_bf16 (N=2 cols);
// A implicit low-rank: A.h = ETA * sum_{s<t} LAMBDA^(t-1-s) (h_s.h) h_s
__global__ __launch_bounds__(1024) void rnn_kernel(
    const uint4* __restrict__ Wp, const float* __restrict__ ZG,
    const float* __restrict__ g, const float* __restrict__ be,
    float* __restrict__ out) {
  __shared__ float  hist[WPB][NHIST][DH];   // 124 KB
  __shared__ float  part[WPB][DH];
  __shared__ ushort hbf[WPB][DH];           // h in bf16 (B-fragment source)
  __shared__ float  h_s[WPB][DH];
  __shared__ float  red1[16], red2[16];
  __shared__ float  cc[WPB][NHIST + 1];
  __shared__ float  lam_pow[NHIST];

  const int tid  = threadIdx.x;
  const int lane = tid & 63;
  const int wave = tid >> 6;        // 0..15
  const int bl   = tid >> 9;        // owner batch-local (0/1)
  const int r    = tid & 511;       // owner row
  const int blw  = wave >> 3;       // batch served in dot phase
  const int c    = lane & 15;       // mfma col
  const int gq   = lane >> 4;       // mfma k-group / row-quad
  const int bg   = blockIdx.x * WPB;

  const int mt0 = 2 * wave, mt1 = 2 * wave + 1;
  const uint4* wpA0 = Wp + (size_t)mt0 * 1024 + lane;
  const uint4* wpA1 = Wp + (size_t)mt1 * 1024 + lane;

  if (tid == 0) {
    float p = 1.f;
    for (int k = 0; k < NHIST; ++k) { lam_pow[k] = p; p *= LAMBDA_; }
  }
  const float g_r = g[r], be_r = be[r];

  // prefetch first 8 K-steps of this wave's W tiles (for t=1)
  uint4 pf0[8], pf1[8];
#pragma unroll
  for (int kk = 0; kk < 8; ++kk) {
    pf0[kk] = wpA0[(size_t)kk * 64];
    pf1[kk] = wpA1[(size_t)kk * 64];
  }

  // per-batch LayerNorm+ReLU; 2 barriers; writes h_s (fp32) + hbf (bf16)
  auto ln = [&](float x) -> float {
    float s1 = x, s2 = x * x;
#pragma unroll
    for (int off = 32; off; off >>= 1) {
      s1 += __shfl_xor(s1, off, 64);
      s2 += __shfl_xor(s2, off, 64);
    }
    if (lane == 0) { red1[wave] = s1; red2[wave] = s2; }
    __syncthreads();
    float a = 0.f, q = 0.f;
#pragma unroll
    for (int w2 = 0; w2 < 8; ++w2) { a += red1[bl * 8 + w2]; q += red2[bl * 8 + w2]; }
    const float mu = a * (1.f / DH);
    const float rs = rsqrtf(q * (1.f / DH) - mu * mu + EPS_);
    const float hv = fmaxf((x - mu) * rs * g_r + be_r, 0.f);
    h_s[bl][r] = hv;
    hbf[bl][r] = (ushort)bf16cvt(hv);
    __syncthreads();
    return hv;
  };

  float hv = 0.f;
  for (int t = 0; t < T_STEPS; ++t) {
    const float zgv = ZG[((size_t)t * BATCH + bg + bl) * DH + r];
    float xb;

    if (t == 0) {
      xb = zgv;
    } else {
      // Phase 1: hb = Wh.h (both batches) via MFMA; wave owns Mtiles mt0,mt1
      f32x4 acc0 = {0.f, 0.f, 0.f, 0.f}, acc1 = {0.f, 0.f, 0.f, 0.f};
#pragma unroll
      for (int kk = 0; kk < 16; ++kk) {
        const uint4 a0u = (kk < 8) ? pf0[kk] : wpA0[(size_t)kk * 64];
        const uint4 a1u = (kk < 8) ? pf1[kk] : wpA1[(size_t)kk * 64];
        uint4 bvu = {0u, 0u, 0u, 0u};
        if (c < WPB)
          bvu = *reinterpret_cast<const uint4*>(&hbf[c][kk * 32 + gq * 8]);
        const short8 a0 = __builtin_bit_cast(short8, a0u);
        const short8 a1 = __builtin_bit_cast(short8, a1u);
        const short8 bv = __builtin_bit_cast(short8, bvu);
        acc0 = __builtin_amdgcn_mfma_f32_16x16x32_bf16(a0, bv, acc0, 0, 0, 0);
        acc1 = __builtin_amdgcn_mfma_f32_16x16x32_bf16(a1, bv, acc1, 0, 0, 0);
      }
      // re-issue prefetch for next step; hides half the W-stream under phases
      if (t < T_STEPS - 1) {
#pragma unroll
        for (int kk = 0; kk < 8; ++kk) {
          pf0[kk] = wpA0[(size_t)kk * 64];
          pf1[kk] = wpA1[(size_t)kk * 64];
        }
      }
      // D layout: col=lane&15, row=(lane>>4)*4+reg  -> rows 4gq..4gq+3
      if (c < WPB) {
        *reinterpret_cast<f32x4*>(&part[c][mt0 * 16 + gq * 4]) = acc0;
        *reinterpret_cast<f32x4*>(&part[c][mt1 * 16 + gq * 4]) = acc1;
      }
      __syncthreads();                                   // B1
      xb = part[bl][r] + zgv;
    }

    // Phase 2: h = relu(LN(hb))
    hv = ln(xb);                                          // B2,B3

    // Phase 3: S_LOOP=2 fast-weight reads (A==0 at t=0 -> skip)
    if (t > 0) {
      for (int s = 0; s < 2; ++s) {
        const float4 c0 = *reinterpret_cast<const float4*>(&h_s[blw][lane * 8]);
        const float4 c1 = *reinterpret_cast<const float4*>(&h_s[blw][lane * 8 + 4]);
        for (int sp = wave & 7; sp < t; sp += 8) {
          const float* hr = hist[blw][sp];
          const float4 a0 = *reinterpret_cast<const float4*>(hr + lane * 8);
          const float4 a1 = *reinterpret_cast<const float4*>(hr + lane * 8 + 4);
          float d = c0.x*a0.x + c0.y*a0.y + c0.z*a0.z + c0.w*a0.w
                  + c1.x*a1.x + c1.y*a1.y + c1.z*a1.z + c1.w*a1.w;
#pragma unroll
          for (int off = 32; off; off >>= 1) d += __shfl_xor(d, off, 64);
          if (lane == 0) cc[blw][sp] = ETA_ * lam_pow[t - 1 - sp] * d;
        }
        __syncthreads();                                  // B4
        float ah = 0.f;
        for (int sp = 0; sp < t; ++sp) ah = fmaf(cc[bl][sp], hist[bl][sp][r], ah);
        hv = ln(xb + ah);                                 // B5,B6
      }
    }

    // Phase 4: append h to history
    if (t < T_STEPS - 1) hist[bl][t][r] = hv;
  }

  out[(size_t)(bg + bl) * DH + r] = hv;
}

extern "C" void kernel_launch(void* const* d_in, const int* in_sizes, int n_in,
                              void* d_out, int out_size, void* d_ws, size_t ws_size,
                              hipStream_t stream) {
  const float* z     = (const float*)d_in[0];  // [T,B,DG]
  const float* W_h   = (const float*)d_in[1];  // [DH,DH]
  const float* W_g   = (const float*)d_in[2];  // [DH,DG]
  const float* b_h   = (const float*)d_in[3];  // [DH]
  const float* gamma = (const float*)d_in[4];  // [DH]
  const float* beta  = (const float*)d_in[5];  // [DH]
  float* out = (float*)d_out;                  // [B,DH]

  float* ZG = (float*)d_ws;                                             // 2 MB
  uint4* Wp = (uint4*)((char*)d_ws + (size_t)T_STEPS * BATCH * DH * 4); // 512 KB

  aux_kernel<<<dim3(320), dim3(512), 0, stream>>>(z, W_g, b_h, ZG, W_h, Wp);
  rnn_kernel<<<dim3(BATCH / WPB), dim3(1024), 0, stream>>>(Wp, ZG, gamma, beta, out);
}

// Round 5
// 513.459 us; speedup vs baseline: 1.0164x; 1.0164x over previous
//
#include <hip/hip_runtime.h>

typedef __attribute__((ext_vector_type(8))) short short8;
typedef __attribute__((ext_vector_type(4))) float f32x4;

constexpr int T_STEPS = 32;
constexpr int BATCH   = 32;
constexpr int DG      = 256;
constexpr int DH      = 512;
constexpr int NHIST   = 31;
constexpr int WPB     = 2;      // batches per block
constexpr float LAMBDA_ = 0.95f;
constexpr float ETA_    = 0.5f;
constexpr float EPS_    = 1e-5f;

__device__ __forceinline__ uint bf16cvt(float f) {
  uint u = __float_as_uint(f);
  return (u + 0x7FFFu + ((u >> 16) & 1u)) >> 16;
}

// aux: blocks 0..255 -> ZG = z @ Wg^T + bh ; blocks 256..319 -> pack W_h into
// MFMA A-fragment layout: Wp[(mt*16+kk)*64 + lane] = uint4 of 8 bf16 =
// W[mt*16 + (lane&15)][kk*32 + (lane>>4)*8 .. +8), lo-first pairs.
__global__ __launch_bounds__(512) void aux_kernel(
    const float* __restrict__ z, const float* __restrict__ Wg,
    const float* __restrict__ bh, float* __restrict__ ZG,
    const float* __restrict__ Wh, uint4* __restrict__ Wp) {
  const int tid = threadIdx.x;
  if (blockIdx.x < 256) {
    const int lane = tid & 63;
    const int wave = tid >> 6;   // 0..7
    const int tb0  = blockIdx.x * 4;
    float4 zv[4];
#pragma unroll
    for (int p = 0; p < 4; ++p)
      zv[p] = *reinterpret_cast<const float4*>(z + (size_t)(tb0 + p) * DG + lane * 4);
    for (int k = 0; k < 64; ++k) {
      const int r = wave * 64 + k;
      const float4 wv = *reinterpret_cast<const float4*>(Wg + (size_t)r * DG + lane * 4);
      float a0 = zv[0].x*wv.x + zv[0].y*wv.y + zv[0].z*wv.z + zv[0].w*wv.w;
      float a1 = zv[1].x*wv.x + zv[1].y*wv.y + zv[1].z*wv.z + zv[1].w*wv.w;
      float a2 = zv[2].x*wv.x + zv[2].y*wv.y + zv[2].z*wv.z + zv[2].w*wv.w;
      float a3 = zv[3].x*wv.x + zv[3].y*wv.y + zv[3].z*wv.z + zv[3].w*wv.w;
#pragma unroll
      for (int off = 32; off; off >>= 1) {
        a0 += __shfl_xor(a0, off, 64);
        a1 += __shfl_xor(a1, off, 64);
        a2 += __shfl_xor(a2, off, 64);
        a3 += __shfl_xor(a3, off, 64);
      }
      if (lane == 0) {
        const float bb = bh[r];
        ZG[(size_t)(tb0 + 0) * DH + r] = a0 + bb;
        ZG[(size_t)(tb0 + 1) * DH + r] = a1 + bb;
        ZG[(size_t)(tb0 + 2) * DH + r] = a2 + bb;
        ZG[(size_t)(tb0 + 3) * DH + r] = a3 + bb;
      }
    }
  } else {
    const int f  = (blockIdx.x - 256) * 512 + tid;   // 0..32767
    const int lf = f & 63;
    const int kk = (f >> 6) & 15;
    const int mt = f >> 10;
    const int r  = mt * 16 + (lf & 15);
    const int k0 = kk * 32 + (lf >> 4) * 8;
    const float4 a = *reinterpret_cast<const float4*>(Wh + (size_t)r * DH + k0);
    const float4 b = *reinterpret_cast<const float4*>(Wh + (size_t)r * DH + k0 + 4);
    uint4 o;
    o.x = bf16cvt(a.x) | (bf16cvt(a.y) << 16);
    o.y = bf16cvt(a.z) | (bf16cvt(a.w) << 16);
    o.z = bf16cvt(b.x) | (bf16cvt(b.y) << 16);
    o.w = bf16cvt(b.z) | (bf16cvt(b.w) << 16);
    Wp[f] = o;
  }
}

// Serial recurrence: 16 blocks x 1024 threads, 2 batches/block, 1 block/CU
// (launch_bounds 4 waves/EU -> 128-VGPR budget: the 8-deep W prefetch fits
// in registers instead of spilling to scratch).
__global__ __launch_bounds__(1024, 4) void rnn_kernel(
    const uint4* __restrict__ Wp, const float* __restrict__ ZG,
    const float* __restrict__ g, const float* __restrict__ be,
    float* __restrict__ out) {
  __shared__ float  hist[WPB][NHIST][DH];   // 124 KB
  __shared__ float  part[WPB][DH];
  __shared__ ushort hbf[WPB][DH];           // h in bf16 (B-fragment source)
  __shared__ float  h_s[WPB][DH];
  __shared__ float  red1[16], red2[16];
  __shared__ float  cc[WPB][NHIST + 1];
  __shared__ float  lam_pow[NHIST];

  const int tid  = threadIdx.x;
  const int lane = tid & 63;
  const int wave = tid >> 6;        // 0..15
  const int bl   = tid >> 9;        // owner batch-local (0/1)
  const int r    = tid & 511;       // owner row
  const int blw  = wave >> 3;       // batch served in dot phase
  const int c    = lane & 15;       // mfma col
  const int gq   = lane >> 4;       // mfma k-group / row-quad
  const int bg   = blockIdx.x * WPB;

  const int mt0 = 2 * wave, mt1 = 2 * wave + 1;
  const uint4* wpA0 = Wp + (size_t)mt0 * 1024 + lane;
  const uint4* wpA1 = Wp + (size_t)mt1 * 1024 + lane;

  if (tid == 0) {
    float p = 1.f;
    for (int k = 0; k < NHIST; ++k) { lam_pow[k] = p; p *= LAMBDA_; }
  }
  const float g_r = g[r], be_r = be[r];

  // prefetch first 8 K-steps of this wave's W tiles (for t=1)
  uint4 pf0[8], pf1[8];
#pragma unroll
  for (int kk = 0; kk < 8; ++kk) {
    pf0[kk] = wpA0[(size_t)kk * 64];
    pf1[kk] = wpA1[(size_t)kk * 64];
  }

  // per-batch LayerNorm+ReLU; 2 barriers; writes h_s (fp32) + hbf (bf16)
  auto ln = [&](float x) -> float {
    float s1 = x, s2 = x * x;
#pragma unroll
    for (int off = 32; off; off >>= 1) {
      s1 += __shfl_xor(s1, off, 64);
      s2 += __shfl_xor(s2, off, 64);
    }
    if (lane == 0) { red1[wave] = s1; red2[wave] = s2; }
    __syncthreads();
    float a = 0.f, q = 0.f;
#pragma unroll
    for (int w2 = 0; w2 < 8; ++w2) { a += red1[bl * 8 + w2]; q += red2[bl * 8 + w2]; }
    const float mu = a * (1.f / DH);
    const float rs = rsqrtf(q * (1.f / DH) - mu * mu + EPS_);
    const float hv = fmaxf((x - mu) * rs * g_r + be_r, 0.f);
    h_s[bl][r] = hv;
    hbf[bl][r] = (ushort)bf16cvt(hv);
    __syncthreads();
    return hv;
  };

  float hv = 0.f;
  for (int t = 0; t < T_STEPS; ++t) {
    const float zgv = ZG[((size_t)t * BATCH + bg + bl) * DH + r];
    float xb;

    if (t == 0) {
      xb = zgv;
    } else {
      // Phase 1: hb = Wh.h (both batches) via MFMA; wave owns Mtiles mt0,mt1
      f32x4 acc0 = {0.f, 0.f, 0.f, 0.f}, acc1 = {0.f, 0.f, 0.f, 0.f};
#pragma unroll
      for (int kk = 0; kk < 16; ++kk) {
        const uint4 a0u = (kk < 8) ? pf0[kk] : wpA0[(size_t)kk * 64];
        const uint4 a1u = (kk < 8) ? pf1[kk] : wpA1[(size_t)kk * 64];
        uint4 bvu = {0u, 0u, 0u, 0u};
        if (c < WPB)
          bvu = *reinterpret_cast<const uint4*>(&hbf[c][kk * 32 + gq * 8]);
        const short8 a0 = __builtin_bit_cast(short8, a0u);
        const short8 a1 = __builtin_bit_cast(short8, a1u);
        const short8 bv = __builtin_bit_cast(short8, bvu);
        acc0 = __builtin_amdgcn_mfma_f32_16x16x32_bf16(a0, bv, acc0, 0, 0, 0);
        acc1 = __builtin_amdgcn_mfma_f32_16x16x32_bf16(a1, bv, acc1, 0, 0, 0);
      }
      // re-issue prefetch for next step; drains during the phases below
      if (t < T_STEPS - 1) {
#pragma unroll
        for (int kk = 0; kk < 8; ++kk) {
          pf0[kk] = wpA0[(size_t)kk * 64];
          pf1[kk] = wpA1[(size_t)kk * 64];
        }
      }
      // D layout: col=lane&15, row=(lane>>4)*4+reg  -> rows 4gq..4gq+3
      if (c < WPB) {
        *reinterpret_cast<f32x4*>(&part[c][mt0 * 16 + gq * 4]) = acc0;
        *reinterpret_cast<f32x4*>(&part[c][mt1 * 16 + gq * 4]) = acc1;
      }
      __syncthreads();                                   // B1
      xb = part[bl][r] + zgv;
    }

    // Phase 2: h = relu(LN(hb))
    hv = ln(xb);                                          // B2,B3

    // Phase 3: S_LOOP=2 fast-weight reads (A==0 at t=0 -> skip)
    if (t > 0) {
      for (int s = 0; s < 2; ++s) {
        // cc[sp] = ETA*lambda^(t-1-sp) * (hist[sp] . h); contiguous b128 reads
        const float4 c0 = *reinterpret_cast<const float4*>(&h_s[blw][lane * 4]);
        const float4 c1 = *reinterpret_cast<const float4*>(&h_s[blw][256 + lane * 4]);
        for (int sp = wave & 7; sp < t; sp += 8) {
          const float* hr = hist[blw][sp];
          const float4 a0 = *reinterpret_cast<const float4*>(hr + lane * 4);
          const float4 a1 = *reinterpret_cast<const float4*>(hr + 256 + lane * 4);
          float d = c0.x*a0.x + c0.y*a0.y + c0.z*a0.z + c0.w*a0.w
                  + c1.x*a1.x + c1.y*a1.y + c1.z*a1.z + c1.w*a1.w;
#pragma unroll
          for (int off = 32; off; off >>= 1) d += __shfl_xor(d, off, 64);
          if (lane == 0) cc[blw][sp] = ETA_ * lam_pow[t - 1 - sp] * d;
        }
        __syncthreads();                                  // B4
        float ah = 0.f;
        for (int sp = 0; sp < t; ++sp) ah = fmaf(cc[bl][sp], hist[bl][sp][r], ah);
        hv = ln(xb + ah);                                 // B5,B6
      }
    }

    // Phase 4: append h to history
    if (t < T_STEPS - 1) hist[bl][t][r] = hv;
  }

  out[(size_t)(bg + bl) * DH + r] = hv;
}

extern "C" void kernel_launch(void* const* d_in, const int* in_sizes, int n_in,
                              void* d_out, int out_size, void* d_ws, size_t ws_size,
                              hipStream_t stream) {
  const float* z     = (const float*)d_in[0];  // [T,B,DG]
  const float* W_h   = (const float*)d_in[1];  // [DH,DH]
  const float* W_g   = (const float*)d_in[2];  // [DH,DG]
  const float* b_h   = (const float*)d_in[3];  // [DH]
  const float* gamma = (const float*)d_in[4];  // [DH]
  const float* beta  = (const float*)d_in[5];  // [DH]
  float* out = (float*)d_out;                  // [B,DH]

  float* ZG = (float*)d_ws;                                             // 2 MB
  uint4* Wp = (uint4*)((char*)d_ws + (size_t)T_STEPS * BATCH * DH * 4); // 512 KB

  aux_kernel<<<dim3(320), dim3(512), 0, stream>>>(z, W_g, b_h, ZG, W_h, Wp);
  rnn_kernel<<<dim3(BATCH / WPB), dim3(1024), 0, stream>>>(Wp, ZG, gamma, beta, out);
}

// Round 6
// 352.067 us; speedup vs baseline: 1.4823x; 1.4584x over previous
//
#include <hip/hip_runtime.h>

typedef __attribute__((ext_vector_type(8))) short short8;
typedef __attribute__((ext_vector_type(4))) float f32x4;

constexpr int T_STEPS = 32;
constexpr int BATCH   = 32;
constexpr int DG      = 256;
constexpr int DH      = 512;
constexpr int NHIST   = 31;
constexpr int WPB     = 2;      // batches per block
constexpr float LAMBDA_ = 0.95f;
constexpr float ETA_    = 0.5f;
constexpr float EPS_    = 1e-5f;

__device__ __forceinline__ uint bf16cvt(float f) {
  uint u = __float_as_uint(f);
  return (u + 0x7FFFu + ((u >> 16) & 1u)) >> 16;
}

// aux: blocks 0..255 -> ZG = z @ Wg^T + bh ; blocks 256..319 -> pack W_h into
// MFMA A-fragment layout: Wp[(mt*16+kk)*64 + lane] = uint4 of 8 bf16 =
// W[mt*16 + (lane&15)][kk*32 + (lane>>4)*8 .. +8), lo-first pairs.
__global__ __launch_bounds__(512) void aux_kernel(
    const float* __restrict__ z, const float* __restrict__ Wg,
    const float* __restrict__ bh, float* __restrict__ ZG,
    const float* __restrict__ Wh, uint4* __restrict__ Wp) {
  const int tid = threadIdx.x;
  if (blockIdx.x < 256) {
    const int lane = tid & 63;
    const int wave = tid >> 6;   // 0..7
    const int tb0  = blockIdx.x * 4;
    float4 zv[4];
#pragma unroll
    for (int p = 0; p < 4; ++p)
      zv[p] = *reinterpret_cast<const float4*>(z + (size_t)(tb0 + p) * DG + lane * 4);
    for (int k = 0; k < 64; ++k) {
      const int r = wave * 64 + k;
      const float4 wv = *reinterpret_cast<const float4*>(Wg + (size_t)r * DG + lane * 4);
      float a0 = zv[0].x*wv.x + zv[0].y*wv.y + zv[0].z*wv.z + zv[0].w*wv.w;
      float a1 = zv[1].x*wv.x + zv[1].y*wv.y + zv[1].z*wv.z + zv[1].w*wv.w;
      float a2 = zv[2].x*wv.x + zv[2].y*wv.y + zv[2].z*wv.z + zv[2].w*wv.w;
      float a3 = zv[3].x*wv.x + zv[3].y*wv.y + zv[3].z*wv.z + zv[3].w*wv.w;
#pragma unroll
      for (int off = 32; off; off >>= 1) {
        a0 += __shfl_xor(a0, off, 64);
        a1 += __shfl_xor(a1, off, 64);
        a2 += __shfl_xor(a2, off, 64);
        a3 += __shfl_xor(a3, off, 64);
      }
      if (lane == 0) {
        const float bb = bh[r];
        ZG[(size_t)(tb0 + 0) * DH + r] = a0 + bb;
        ZG[(size_t)(tb0 + 1) * DH + r] = a1 + bb;
        ZG[(size_t)(tb0 + 2) * DH + r] = a2 + bb;
        ZG[(size_t)(tb0 + 3) * DH + r] = a3 + bb;
      }
    }
  } else {
    const int f  = (blockIdx.x - 256) * 512 + tid;   // 0..32767
    const int lf = f & 63;
    const int kk = (f >> 6) & 15;
    const int mt = f >> 10;
    const int r  = mt * 16 + (lf & 15);
    const int k0 = kk * 32 + (lf >> 4) * 8;
    const float4 a = *reinterpret_cast<const float4*>(Wh + (size_t)r * DH + k0);
    const float4 b = *reinterpret_cast<const float4*>(Wh + (size_t)r * DH + k0 + 4);
    uint4 o;
    o.x = bf16cvt(a.x) | (bf16cvt(a.y) << 16);
    o.y = bf16cvt(a.z) | (bf16cvt(a.w) << 16);
    o.z = bf16cvt(b.x) | (bf16cvt(b.y) << 16);
    o.w = bf16cvt(b.z) | (bf16cvt(b.w) << 16);
    Wp[f] = o;
  }
}

// Serial recurrence: 16 blocks x 1024 threads, 2 batches/block, 1 block/CU.
// K-loop: plain unrolled direct loads -> MFMA. No hand-built prefetch arrays
// (round-5 post-mortem: an 8-deep register pipeline = 128 VGPRs = scratch
// spill; port saturation only needs ~2 loads in flight per wave, which the
// compiler's own hoisting provides within budget).
__global__ __launch_bounds__(1024, 4) void rnn_kernel(
    const uint4* __restrict__ Wp, const float* __restrict__ ZG,
    const float* __restrict__ g, const float* __restrict__ be,
    float* __restrict__ out) {
  __shared__ float  hist[WPB][NHIST][DH];   // 124 KB
  __shared__ float  part[WPB][DH];
  __shared__ ushort hbf[WPB][DH];           // h in bf16 (B-fragment source)
  __shared__ float  h_s[WPB][DH];
  __shared__ float  red1[16], red2[16];
  __shared__ float  cc[WPB][NHIST + 1];
  __shared__ float  lam_pow[NHIST];

  const int tid  = threadIdx.x;
  const int lane = tid & 63;
  const int wave = tid >> 6;        // 0..15
  const int bl   = tid >> 9;        // owner batch-local (0/1)
  const int r    = tid & 511;       // owner row
  const int blw  = wave >> 3;       // batch served in dot phase
  const int c    = lane & 15;       // mfma col
  const int gq   = lane >> 4;       // mfma k-group / row-quad
  const int bg   = blockIdx.x * WPB;

  const int mt0 = 2 * wave, mt1 = 2 * wave + 1;
  const uint4* wpA0 = Wp + (size_t)mt0 * 1024 + lane;
  const uint4* wpA1 = Wp + (size_t)mt1 * 1024 + lane;

  if (tid == 0) {
    float p = 1.f;
    for (int k = 0; k < NHIST; ++k) { lam_pow[k] = p; p *= LAMBDA_; }
  }
  const float g_r = g[r], be_r = be[r];

  // per-batch LayerNorm+ReLU; 2 barriers; writes h_s (fp32) + hbf (bf16)
  auto ln = [&](float x) -> float {
    float s1 = x, s2 = x * x;
#pragma unroll
    for (int off = 32; off; off >>= 1) {
      s1 += __shfl_xor(s1, off, 64);
      s2 += __shfl_xor(s2, off, 64);
    }
    if (lane == 0) { red1[wave] = s1; red2[wave] = s2; }
    __syncthreads();
    float a = 0.f, q = 0.f;
#pragma unroll
    for (int w2 = 0; w2 < 8; ++w2) { a += red1[bl * 8 + w2]; q += red2[bl * 8 + w2]; }
    const float mu = a * (1.f / DH);
    const float rs = rsqrtf(q * (1.f / DH) - mu * mu + EPS_);
    const float hv = fmaxf((x - mu) * rs * g_r + be_r, 0.f);
    h_s[bl][r] = hv;
    hbf[bl][r] = (ushort)bf16cvt(hv);
    __syncthreads();
    return hv;
  };

  float hv = 0.f;
  for (int t = 0; t < T_STEPS; ++t) {
    const float zgv = ZG[((size_t)t * BATCH + bg + bl) * DH + r];
    float xb;

    if (t == 0) {
      xb = zgv;
    } else {
      // Phase 1: hb = Wh.h (both batches) via MFMA; wave owns Mtiles mt0,mt1.
      // Direct loads; full unroll lets the compiler keep several K-tiles of
      // W in flight (port saturation needs only ~2KB/wave outstanding).
      f32x4 acc0 = {0.f, 0.f, 0.f, 0.f}, acc1 = {0.f, 0.f, 0.f, 0.f};
#pragma unroll
      for (int kk = 0; kk < 16; ++kk) {
        const uint4 a0u = wpA0[(size_t)kk * 64];
        const uint4 a1u = wpA1[(size_t)kk * 64];
        uint4 bvu = {0u, 0u, 0u, 0u};
        if (c < WPB)
          bvu = *reinterpret_cast<const uint4*>(&hbf[c][kk * 32 + gq * 8]);
        const short8 a0 = __builtin_bit_cast(short8, a0u);
        const short8 a1 = __builtin_bit_cast(short8, a1u);
        const short8 bv = __builtin_bit_cast(short8, bvu);
        acc0 = __builtin_amdgcn_mfma_f32_16x16x32_bf16(a0, bv, acc0, 0, 0, 0);
        acc1 = __builtin_amdgcn_mfma_f32_16x16x32_bf16(a1, bv, acc1, 0, 0, 0);
      }
      // D layout: col=lane&15, row=(lane>>4)*4+reg  -> rows 4gq..4gq+3
      if (c < WPB) {
        *reinterpret_cast<f32x4*>(&part[c][mt0 * 16 + gq * 4]) = acc0;
        *reinterpret_cast<f32x4*>(&part[c][mt1 * 16 + gq * 4]) = acc1;
      }
      __syncthreads();                                   // B1
      xb = part[bl][r] + zgv;
    }

    // Phase 2: h = relu(LN(hb))
    hv = ln(xb);                                          // B2,B3

    // Phase 3: S_LOOP=2 fast-weight reads (A==0 at t=0 -> skip)
    if (t > 0) {
      for (int s = 0; s < 2; ++s) {
        // cc[sp] = ETA*lambda^(t-1-sp) * (hist[sp] . h); contiguous b128 reads
        const float4 c0 = *reinterpret_cast<const float4*>(&h_s[blw][lane * 4]);
        const float4 c1 = *reinterpret_cast<const float4*>(&h_s[blw][256 + lane * 4]);
        for (int sp = wave & 7; sp < t; sp += 8) {
          const float* hr = hist[blw][sp];
          const float4 a0 = *reinterpret_cast<const float4*>(hr + lane * 4);
          const float4 a1 = *reinterpret_cast<const float4*>(hr + 256 + lane * 4);
          float d = c0.x*a0.x + c0.y*a0.y + c0.z*a0.z + c0.w*a0.w
                  + c1.x*a1.x + c1.y*a1.y + c1.z*a1.z + c1.w*a1.w;
#pragma unroll
          for (int off = 32; off; off >>= 1) d += __shfl_xor(d, off, 64);
          if (lane == 0) cc[blw][sp] = ETA_ * lam_pow[t - 1 - sp] * d;
        }
        __syncthreads();                                  // B4
        float ah = 0.f;
        for (int sp = 0; sp < t; ++sp) ah = fmaf(cc[bl][sp], hist[bl][sp][r], ah);
        hv = ln(xb + ah);                                 // B5,B6
      }
    }

    // Phase 4: append h to history
    if (t < T_STEPS - 1) hist[bl][t][r] = hv;
  }

  out[(size_t)(bg + bl) * DH + r] = hv;
}

extern "C" void kernel_launch(void* const* d_in, const int* in_sizes, int n_in,
                              void* d_out, int out_size, void* d_ws, size_t ws_size,
                              hipStream_t stream) {
  const float* z     = (const float*)d_in[0];  // [T,B,DG]
  const float* W_h   = (const float*)d_in[1];  // [DH,DH]
  const float* W_g   = (const float*)d_in[2];  // [DH,DG]
  const float* b_h   = (const float*)d_in[3];  // [DH]
  const float* gamma = (const float*)d_in[4];  // [DH]
  const float* beta  = (const float*)d_in[5];  // [DH]
  float* out = (float*)d_out;                  // [B,DH]

  float* ZG = (float*)d_ws;                                             // 2 MB
  uint4* Wp = (uint4*)((char*)d_ws + (size_t)T_STEPS * BATCH * DH * 4); // 512 KB

  aux_kernel<<<dim3(320), dim3(512), 0, stream>>>(z, W_g, b_h, ZG, W_h, Wp);
  rnn_kernel<<<dim3(BATCH / WPB), dim3(1024), 0, stream>>>(Wp, ZG, gamma, beta, out);
}